// Round 12
// baseline (3057.423 us; speedup 1.0000x reference)
//
#include <hip/hip_runtime.h>
#include <math.h>

#define Nn 2048
#define Dd 128
#define Vv 3
#define VDd 512
#define Kk 10
#define VHh 12

typedef unsigned short u16;

__device__ __forceinline__ float bf2f(u16 u){
  union { unsigned int i; float f; } t; t.i = ((unsigned int)u) << 16; return t.f;
}
// Adaptive guarded input load: element idx of an array of n elements whose
// storage dtype is f32 (isf32=1) or bf16 (isf32=0). Never OOB; n==0 safe.
__device__ __forceinline__ float ldx(const void* p, unsigned idx, unsigned n, int isf32){
  if (idx >= n) return 0.f;
  return isf32 ? ((const float*)p)[idx] : bf2f(((const u16*)p)[idx]);
}
__device__ __forceinline__ float ldf(const float* p, unsigned idx, unsigned n){
  return (idx < n) ? p[idx] : 0.f;
}
__device__ __forceinline__ double ldd(const double* p, unsigned idx, unsigned n){
  return (idx < n) ? p[idx] : 0.0;
}
__device__ __forceinline__ int ldi(const int* p, unsigned idx, unsigned n){
  return (idx < n) ? p[idx] : 0;
}
__device__ __forceinline__ void stf(float* p, unsigned idx, unsigned n, float v){
  if (idx < n) p[idx] = v;     // OUTPUTS ARE FLOAT32 (r11 post-mortem)
}

// ---------- input-dtype detector: bf16 read of f32 data => ~22% garbage ----------
__global__ __launch_bounds__(256) void detect_k(const u16* __restrict__ lat, unsigned nlat,
                                                int* __restrict__ flagp, int ok){
  if (!ok) return;
  int t = threadIdx.x;
  int bad = 0;
  for (unsigned i = t; i < 8192u && i < nlat; i += 256u){
    float x = bf2f(lat[i]);
    if (!(x == x) || fabsf(x) > 1e4f) bad++;
  }
  __shared__ int sb[256];
  sb[t] = bad; __syncthreads();
  for (int o = 128; o > 0; o >>= 1){ if (t < o) sb[t] += sb[t+o]; __syncthreads(); }
  if (t == 0) flagp[0] = (sb[0] > 409) ? 1 : 0;   // >5% garbage => inputs are f32
}

// ---------- sq[i] = sum_d latent[i,d]^2 (f64 exact) ----------
__global__ __launch_bounds__(128) void sq_k(const void* __restrict__ lat, unsigned nlat,
                                            double* __restrict__ sq, unsigned nsq,
                                            const int* __restrict__ flagp, int fok){
  int isf32 = fok ? flagp[0] : 0;
  unsigned i = blockIdx.x; int t = threadIdx.x;
  float x = ldx(lat, i*Dd + t, nlat, isf32);
  double p = (double)x * (double)x;
#pragma unroll
  for (int o=32;o>0;o>>=1) p += __shfl_down(p, o);
  __shared__ double s2[2];
  if ((t&63)==0) s2[t>>6] = p;
  __syncthreads();
  if (t==0 && i < nsq) sq[i] = s2[0] + s2[1];
}

// ---------- WH[vh,n,e] = sum_d latent[n,d]*gatW[vh,d,e] ----------
__global__ __launch_bounds__(256) void wh_k(const void* __restrict__ lat, unsigned nlat,
                                            const void* __restrict__ gw, unsigned ngw,
                                            float* __restrict__ WH, unsigned nwh,
                                            const int* __restrict__ flagp, int fok){
  int isf32 = fok ? flagp[0] : 0;
  unsigned idx = blockIdx.x*256u + threadIdx.x;      // [vh(12)][n(2048)][e(128)]
  unsigned e = idx & 127u, n = (idx >> 7) & 2047u, vh = idx >> 18;
  float acc = 0.f;
  for (int d=0; d<Dd; d++)
    acc += ldx(lat, n*Dd + d, nlat, isf32) * ldx(gw, (vh*Dd + d)*Dd + e, ngw, isf32);
  if (idx < nwh) WH[idx] = acc;
}

// ---------- F1/F2[vh,n] = sum_e WH[vh,n,e]*gat_a[vh,(0|128)+e] ----------
__global__ __launch_bounds__(128) void f12_k(const float* __restrict__ WH, unsigned nwh,
                                             const void* __restrict__ ga, unsigned nga,
                                             float* __restrict__ F1, float* __restrict__ F2,
                                             unsigned nf,
                                             const int* __restrict__ flagp, int fok){
  int isf32 = fok ? flagp[0] : 0;
  unsigned b = blockIdx.x;                 // vh*2048 + n
  unsigned vh = b >> 11;
  int t = threadIdx.x;
  float w = ldf(WH, b*128u + t, nwh);
  float p1 = w * ldx(ga, vh*256u + t, nga, isf32);
  float p2 = w * ldx(ga, vh*256u + 128u + t, nga, isf32);
#pragma unroll
  for (int o=32;o>0;o>>=1){ p1 += __shfl_down(p1,o); p2 += __shfl_down(p2,o); }
  __shared__ float red[4];
  if ((t&63)==0){ red[t>>6] = p1; red[2+(t>>6)] = p2; }
  __syncthreads();
  if (t==0 && b < nf){ F1[b] = red[0]+red[1]; F2[b] = red[2]+red[3]; }
}

// ---------- per-row top-10 by f64-exact squared distance ----------
__global__ __launch_bounds__(64) void knn_k(const void* __restrict__ lat, unsigned nlat,
                                            const double* __restrict__ sq, unsigned nsq,
                                            int* __restrict__ IDX, unsigned nidx,
                                            const int* __restrict__ flagp, int fok){
  int isf32 = fok ? flagp[0] : 0;
  unsigned i = blockIdx.x; int l = threadIdx.x;     // one wave per row
  __shared__ float jt[64][129];
  __shared__ float ir[Dd];
  __shared__ double lv[64][10];
  __shared__ int    li[64][10];
  for (int q=l; q<Dd; q+=64) ir[q] = ldx(lat, i*Dd + q, nlat, isf32);
  double bv[10]; int bix[10];
#pragma unroll
  for (int k=0;k<10;k++){ bv[k] = 1.0e300; bix[k] = 0x7fffffff; }
  for (int tile=0; tile<32; tile++){
    __syncthreads();
    for (int q=l; q<64*Dd; q+=64)
      jt[q>>7][q&127] = ldx(lat, tile*8192u + q, nlat, isf32);
    __syncthreads();
    int j = tile*64 + l;
    double a0 = 0.0, a1 = 0.0;
#pragma unroll 16
    for (int d=0; d<Dd; d+=2){
      a0 += (double)ir[d]   * (double)jt[l][d];
      a1 += (double)ir[d+1] * (double)jt[l][d+1];
    }
    double c = ldd(sq, (unsigned)j, nsq) - 2.0*(a0 + a1);  // sq_i cancels per-row
    if (c < bv[9] || (c == bv[9] && j < bix[9])){
      bv[9] = c; bix[9] = j;
#pragma unroll
      for (int k=9;k>0;k--){
        bool sw = (bv[k] < bv[k-1]) || (bv[k]==bv[k-1] && bix[k] < bix[k-1]);
        if (sw){ double tv=bv[k]; bv[k]=bv[k-1]; bv[k-1]=tv;
                 int ti=bix[k]; bix[k]=bix[k-1]; bix[k-1]=ti; }
      }
    }
  }
  __syncthreads();
#pragma unroll
  for (int k=0;k<10;k++){ lv[l][k] = bv[k]; li[l][k] = bix[k]; }
  int p = 0;
  for (int pass=0; pass<10; pass++){
    double mv = (p<10) ? lv[l][p] : 1.0e301;
    int   mi = (p<10) ? li[l][p] : 0x7fffffff;
    int   ml = l;
#pragma unroll
    for (int o=32;o>0;o>>=1){
      double ov = __shfl_xor(mv, o); int oi = __shfl_xor(mi, o); int ol = __shfl_xor(ml, o);
      if (ov < mv || (ov == mv && oi < mi)){ mv=ov; mi=oi; ml=ol; }
    }
    if (l == 0 && i*Kk + pass < nidx) IDX[i*Kk + pass] = mi;
    if (l == ml) p++;
  }
}

// ---------- sparse GAT attention + semantic (one block per row) ----------
__global__ __launch_bounds__(128) void attnsem_k(const void* __restrict__ FM, unsigned nfm,
                                                 const float* __restrict__ F1,
                                                 const float* __restrict__ F2, unsigned nf,
                                                 const float* __restrict__ WH, unsigned nwh,
                                                 const int* __restrict__ IDX, unsigned nidx,
                                                 const void* __restrict__ AW, unsigned naw,
                                                 const void* __restrict__ AB, unsigned nab,
                                                 float* __restrict__ out, unsigned nout,
                                                 unsigned soff,
                                                 const int* __restrict__ flagp, int fok){
  int isf32 = fok ? flagp[0] : 0;
  unsigned i = blockIdx.x; int t = threadIdx.x;
  __shared__ float hp[Dd];
  int cj[11]; bool self_in = false;
#pragma unroll
  for (int k=0;k<10;k++){
    int j = ldi(IDX, i*Kk + k, nidx);
    j = (j < 0) ? 0 : ((j > Nn-1) ? Nn-1 : j);
    cj[k] = j; self_in = self_in || (j == (int)i);
  }
  cj[10] = (int)i;
  float semacc = 0.f;
  for (int vh=0; vh<VHh; vh++){
    int v = vh >> 2;
    float f1i = ldf(F1, vh*Nn + i, nf);
    float fmi = ldx(FM, i*Vv + v, nfm, isf32);
    float ce[11];
#pragma unroll
    for (int k=0;k<10;k++){
      int j = cj[k];
      float fmj = ldx(FM, j*Vv + v, nfm, isf32);
      float e = f1i + ldf(F2, vh*Nn + j, nf);
      e = (e >= 0.f) ? e : 0.2f*e;
      bool pr = (j == (int)i) || (fmi*fmj > 0.f);
      ce[k] = pr ? e : -INFINITY;
    }
    {
      float e = f1i + ldf(F2, vh*Nn + i, nf);
      e = (e >= 0.f) ? e : 0.2f*e;
      ce[10] = self_in ? -INFINITY : e;
    }
    float m = ce[0];
#pragma unroll
    for (int k=1;k<11;k++) m = fmaxf(m, ce[k]);
    float s = 0.f; float cp[11];
#pragma unroll
    for (int k=0;k<11;k++){ float p = expf(ce[k]-m); cp[k]=p; s+=p; }
    float inv = 1.f/s;
    float hpt = 0.f;
#pragma unroll
    for (int k=0;k<11;k++)
      hpt += cp[k]*inv * ldf(WH, ((unsigned)vh*Nn + cj[k])*Dd + t, nwh);
    __syncthreads();               // hp from previous vh fully consumed
    hp[t] = hpt;
    __syncthreads();
    for (int kk=0; kk<Dd; kk++)
      semacc += hp[kk] * ldx(AW, ((unsigned)vh*Dd + kk)*Dd + t, naw, isf32);
  }
  semacc += ldx(AB, t, nab, isf32);
  stf(out, soff + i*Dd + t, nout, semacc);
}

// ---------- logits = elu(sem@cls_W + b); log_softmax ----------
__global__ __launch_bounds__(128) void cls_k(const float* __restrict__ out_ro, unsigned nout,
                                             unsigned soff, unsigned loff,
                                             const void* __restrict__ CW, unsigned ncw,
                                             const void* __restrict__ Cb, unsigned ncb,
                                             float* __restrict__ out,
                                             const int* __restrict__ flagp, int fok){
  int isf32 = fok ? flagp[0] : 0;
  unsigned i = blockIdx.x; int t = threadIdx.x;
  __shared__ float srow[Dd]; __shared__ float red[4];
  srow[t] = ldf(out_ro, soff + i*Dd + t, nout);    // semantic written by us as f32
  __syncthreads();
  float acc = ldx(Cb, t, ncb, isf32);
  for (int d=0; d<Dd; d++)
    acc += srow[d] * ldx(CW, d*Dd + t, ncw, isf32);
  float lg = (acc > 0.f) ? acc : expm1f(acc);
  float m = lg;
#pragma unroll
  for (int o=32;o>0;o>>=1) m = fmaxf(m, __shfl_xor(m, o));
  if ((t&63)==0) red[t>>6] = m;
  __syncthreads();
  float M = fmaxf(red[0], red[1]);
  float p = expf(lg - M);
  float s = p;
#pragma unroll
  for (int o=32;o>0;o>>=1) s += __shfl_xor(s, o);
  if ((t&63)==0) red[2 + (t>>6)] = s;
  __syncthreads();
  float S2 = red[2] + red[3];
  stf(out, loff + i*Dd + t, nout, lg - M - logf(S2));
}

// ---------- rec[v,n,e] = sum_d latent[n,d]*enc_W[v,d,e] + enc_b[v,e] ----------
__global__ __launch_bounds__(256) void rec_k(const void* __restrict__ lat, unsigned nlat,
                                             const void* __restrict__ ew, unsigned new_,
                                             const void* __restrict__ eb, unsigned neb,
                                             float* __restrict__ out, unsigned nout,
                                             const int* __restrict__ flagp, int fok){
  int isf32 = fok ? flagp[0] : 0;
  unsigned idx = blockIdx.x*256u + threadIdx.x;      // [v(3)][n(2048)][e(512)]
  unsigned e = idx & 511u, n = (idx >> 9) & 2047u, v = idx >> 20;
  float acc = 0.f;
  for (int d=0; d<Dd; d++)
    acc += ldx(lat, n*Dd + d, nlat, isf32) * ldx(ew, (v*Dd + d)*VDd + e, new_, isf32);
  acc += ldx(eb, v*VDd + e, neb, isf32);
  stf(out, idx, nout, acc);
}

extern "C" void kernel_launch(void* const* d_in, const int* in_sizes, int n_in,
                              void* d_out, int out_size, void* d_ws, size_t ws_size,
                              hipStream_t stream){
  const void* FM   = d_in[0];  unsigned nfm  = (unsigned)in_sizes[0];
  const void* LAT  = d_in[1];  unsigned nlat = (unsigned)in_sizes[1];
  const void* ENCW = d_in[2];  unsigned nencw= (unsigned)in_sizes[2];
  const void* ENCB = d_in[3];  unsigned nencb= (unsigned)in_sizes[3];
  const void* GATW = d_in[4];  unsigned ngatw= (unsigned)in_sizes[4];
  const void* GATA = d_in[5];  unsigned ngata= (unsigned)in_sizes[5];
  const void* AGGW = d_in[6];  unsigned naggw= (unsigned)in_sizes[6];
  const void* AGGB = d_in[7];  unsigned naggb= (unsigned)in_sizes[7];
  const void* CLSW = d_in[8];  unsigned nclsw= (unsigned)in_sizes[8];
  const void* CLSB = d_in[9];  unsigned nclsb= (unsigned)in_sizes[9];
  float* out = (float*)d_out;            // OUTPUTS ARE FLOAT32
  unsigned nout = (unsigned)out_size;
  unsigned loff = 3145728u;      // log_softmax region offset (elements)
  unsigned soff = 3407872u;      // semantic region offset

  char* ws = (char*)d_ws;
  int wsok = (d_ws != nullptr && ws_size >= 12877844) ? 1 : 0;
  float*  WH  = (float*)ws;                     unsigned nwh  = wsok ? 3145728u : 0u;
  double* SQ  = (double*)(ws + 12582912);       unsigned nsq  = wsok ? 2048u    : 0u;
  float*  F1  = (float*)(ws + 12599296);
  float*  F2  = (float*)(ws + 12697600);        unsigned nf   = wsok ? 24576u   : 0u;
  int*    IDX = (int*)(ws + 12795904);          unsigned nidx = wsok ? 20480u   : 0u;
  int*    FLAG= (int*)(ws + 12877824);          int fok = wsok;

  hipLaunchKernelGGL(detect_k,  dim3(1),     dim3(256), 0, stream, (const u16*)LAT, nlat, FLAG, fok);
  hipLaunchKernelGGL(sq_k,      dim3(2048),  dim3(128), 0, stream, LAT, nlat, SQ, nsq, FLAG, fok);
  hipLaunchKernelGGL(wh_k,      dim3(12288), dim3(256), 0, stream, LAT, nlat, GATW, ngatw, WH, nwh, FLAG, fok);
  hipLaunchKernelGGL(f12_k,     dim3(24576), dim3(128), 0, stream, WH, nwh, GATA, ngata, F1, F2, nf, FLAG, fok);
  hipLaunchKernelGGL(knn_k,     dim3(2048),  dim3(64),  0, stream, LAT, nlat, SQ, nsq, IDX, nidx, FLAG, fok);
  hipLaunchKernelGGL(attnsem_k, dim3(2048),  dim3(128), 0, stream, FM, nfm, F1, F2, nf, WH, nwh,
                     IDX, nidx, AGGW, naggw, AGGB, naggb, out, nout, soff, FLAG, fok);
  hipLaunchKernelGGL(cls_k,     dim3(2048),  dim3(128), 0, stream, out, nout, soff, loff,
                     CLSW, nclsw, CLSB, nclsb, out, FLAG, fok);
  hipLaunchKernelGGL(rec_k,     dim3(12288), dim3(256), 0, stream, LAT, nlat, ENCW, nencw,
                     ENCB, nencb, out, nout, FLAG, fok);
}